// Round 5
// baseline (936.113 us; speedup 1.0000x reference)
//
#include <hip/hip_runtime.h>

#define L 50
#define NA 120
#define NB 8
#define NPIX 2500
#define NFREQ 51
#define NFULL 100
#define IST 52                 // padded inner stride (16B-aligned rows)
#define ISPEC (NFULL * IST)    // 5200 float2 per spectrum
#define ASTEP 0.026179938779914944f   // pi/120
#define PHI   0.06283185307179586f    // 2*pi/100

// workspace layout in floats
#define OFF_REC  0                    // 8*2*2500 = 40000
#define OFF_LIG  40000                // 40000
#define OFF_F1   80000                // 16 * 5200 f2 = 166400 floats
#define OFF_PVAL 246400               // 960
#define OFF_PIDX 247360               // 960

#define CROT(wx, wy, sx, sy) { float nx_ = fmaf(wx, sx, -(wy) * (sy)); \
                               float ny_ = fmaf(wx, sy,  (wy) * (sx)); \
                               wx = nx_; wy = ny_; }

// ---------------- conv 3x3 (SAME) + bias; ligand channels combined with
// scorer weights (linearity: rotate/FFT commute with the real combine) ------
__global__ __launch_bounds__(256) void k_conv(
    const float* __restrict__ rec, const float* __restrict__ lig,
    const float* __restrict__ cw, const float* __restrict__ cb,
    const float* __restrict__ sw,
    float* __restrict__ rec_feat, float* __restrict__ lig_comb) {
  int t = blockIdx.x * blockDim.x + threadIdx.x;
  if (t >= NB * NPIX) return;
  int b = t / NPIX, p = t % NPIX;
  int i = p / L, j = p % L;
  float r0 = cb[0], r1 = cb[1], l0 = cb[0], l1 = cb[1];
  for (int di = 0; di < 3; ++di) {
    int ii = i + di - 1;
    if (ii < 0 || ii >= L) continue;
    for (int dj = 0; dj < 3; ++dj) {
      int jj = j + dj - 1;
      if (jj < 0 || jj >= L) continue;
      float w0 = cw[di * 3 + dj], w1 = cw[9 + di * 3 + dj];
      float xv = rec[b * NPIX + ii * L + jj];
      float yv = lig[b * NPIX + ii * L + jj];
      r0 += w0 * xv; r1 += w1 * xv;
      l0 += w0 * yv; l1 += w1 * yv;
    }
  }
  rec_feat[(b * 2 + 0) * NPIX + p] = r0;
  rec_feat[(b * 2 + 1) * NPIX + p] = r1;
  lig_comb[(b * 2 + 0) * NPIX + p] = sw[0] * l0 + sw[1] * l1;
  lig_comb[(b * 2 + 1) * NPIX + p] = sw[2] * l0 + sw[3] * l1;
}

// ---- rowDFT full-image helper (k_fwd_rec only): thread (k, rg) -------------
__device__ __forceinline__ void rowdft(const float* img, float2* Arow, int tid) {
  if (tid < 255) {
    const int kR = tid % 51, rgR = tid / 51;   // rows rgR + 5t, t<10
    float are[10], aim[10];
#pragma unroll
    for (int t = 0; t < 10; ++t) { are[t] = 0.f; aim[t] = 0.f; }
    float stx, sty;
    sincosf(PHI * (float)kR, &sty, &stx); sty = -sty;
    for (int half = 0; half < 2; ++half) {
      int u0 = half ? 6 : 0, u1 = half ? 13 : 6;
      float wx, wy;
      int t0 = half ? (24 * kR) % 100 : 0;
      sincosf(PHI * (float)t0, &wy, &wx); wy = -wy;
      for (int u = u0; u < u1; ++u) {
        float4 q[10];
#pragma unroll
        for (int t = 0; t < 10; ++t)
          q[t] = *(const float4*)(img + (rgR + 5 * t) * IST + 4 * u);
#pragma unroll
        for (int v = 0; v < 4; ++v) {
#pragma unroll
          for (int t = 0; t < 10; ++t) {
            float val = (v == 0) ? q[t].x : (v == 1) ? q[t].y : (v == 2) ? q[t].z : q[t].w;
            are[t] = fmaf(val, wx, are[t]);
            aim[t] = fmaf(val, wy, aim[t]);
          }
          CROT(wx, wy, stx, sty);
        }
      }
    }
#pragma unroll
    for (int t = 0; t < 10; ++t)
      Arow[(rgR + 5 * t) * IST + kR] = make_float2(are[t], aim[t]);
  }
}

// ---- colDFT radix-2 helper (k_fwd_rec only) -------------------------------
__device__ __forceinline__ void coldft(const float2* Arow, int mp, int k0,
                                       float* Ex, float* Ey, float* Ox, float* Oy) {
#pragma unroll
  for (int i = 0; i < 14; ++i) { Ex[i] = 0.f; Ey[i] = 0.f; Ox[i] = 0.f; Oy[i] = 0.f; }
  float stx, sty;
  sincosf(PHI * (float)((2 * mp) % 100), &sty, &stx); sty = -sty;
  { float wx = 1.f, wy = 0.f;
    for (int s = 0; s < 25; ++s) {
      const float2* ap = Arow + (2 * s) * IST + k0;
#pragma unroll
      for (int i = 0; i < 14; ++i) {
        float2 q = ap[i];
        Ex[i] = fmaf(q.x, wx, fmaf(-q.y, wy, Ex[i]));
        Ey[i] = fmaf(q.x, wy, fmaf( q.y, wx, Ey[i]));
      }
      CROT(wx, wy, stx, sty);
    } }
  { float wx, wy;
    sincosf(PHI * (float)mp, &wy, &wx); wy = -wy;
    for (int s = 0; s < 25; ++s) {
      const float2* ap = Arow + (2 * s + 1) * IST + k0;
#pragma unroll
      for (int i = 0; i < 14; ++i) {
        float2 q = ap[i];
        Ox[i] = fmaf(q.x, wx, fmaf(-q.y, wy, Ox[i]));
        Oy[i] = fmaf(q.x, wy, fmaf( q.y, wx, Oy[i]));
      }
      CROT(wx, wy, stx, sty);
    } }
}

// ---------------- forward rfft2 of receptor channels (16 images) -----------
__global__ __launch_bounds__(256, 3) void k_fwd_rec(
    const float* __restrict__ src, float2* __restrict__ F1w) {
  __shared__ __align__(16) float img[50 * IST];
  __shared__ __align__(16) float2 Arow[50 * IST + 8];
  const int tid = threadIdx.x, im = blockIdx.x;
  for (int o = tid; o < 50 * IST; o += 256) {
    int i = o / IST, j = o - i * IST;
    img[o] = (j < 50) ? src[im * NPIX + i * 50 + j] : 0.f;
  }
  __syncthreads();
  rowdft(img, Arow, tid);
  __syncthreads();
  if (tid < 200) {
    const int mp = tid % 50, kc = tid / 50;
    const int k0 = (kc < 2) ? kc * 14 : 28 + (kc - 2) * 12;
    const int CW = (kc < 2) ? 14 : 12;
    float Ex[14], Ey[14], Ox[14], Oy[14];
    coldft(Arow, mp, k0, Ex, Ey, Ox, Oy);
    float2* d0 = F1w + (size_t)im * ISPEC + mp * IST + k0;
    float2* d1 = d0 + 50 * IST;
#pragma unroll
    for (int i = 0; i < 14; ++i)
      if (i < CW && k0 + i < 51) {
        d0[i] = make_float2(Ex[i] + Ox[i], Ey[i] + Oy[i]);
        d1[i] = make_float2(Ex[i] - Ox[i], Ey[i] - Oy[i]);
      }
  }
}

// ---------------- fused per-(angle,batch): rotate -> rfft2 -> product
// (P in LDS) -> radix-2 inverse -> argmax. 48.7 KB LDS -> 3 blocks/CU. ------
__global__ __launch_bounds__(256, 3) void k_dock(
    const float* __restrict__ lig_comb, const float2* __restrict__ F1,
    float* __restrict__ pval, int* __restrict__ pidx) {
  __shared__ __align__(16) float2 P[100 * 52];      // 41.6 KB; later T[51][100]
  __shared__ __align__(16) float2 Arow10[10 * 52];  // 4.16 KB strip spectrum
  __shared__ __align__(16) float imgS[10 * 52];     // 2.08 KB strip image
  __shared__ float rv[256];
  __shared__ int ri[256];

  const int tid = threadIdx.x;
  const int ab = blockIdx.x, a = ab / NB, b = ab % NB;
  float sa, ca; sincosf((float)a * ASTEP, &sa, &ca);

  const int mp = tid % 50;                 // m' / r' / c'
  const int kc = tid / 50;                 // 5 chunks; active when tid<250
  const bool act = tid < 250;
  const int k0 = (kc == 0) ? 0 : 11 + 10 * (kc - 1);  // widths 11,10,10,10,10
  const int W  = (kc == 0) ? 11 : 10;
  const int kR = tid % 51, rl = tid / 51;  // rowdft mapping (tid<255)

  float Ex[11], Ey[11], Ox[11], Oy[11];
  float s2x, s2y;                          // e^{-i*2phi*mp}
  sincosf(PHI * (float)((2 * mp) % 100), &s2y, &s2x); s2y = -s2y;

  for (int f = 0; f < 2; ++f) {
    float ewx = 1.f, ewy = 0.f;            // e^{-i phi mp r}, r=0 (even rows)
    float owx, owy;                        // r=1 (odd rows)
    sincosf(PHI * (float)mp, &owy, &owx); owy = -owy;
#pragma unroll
    for (int i = 0; i < 11; ++i) { Ex[i] = 0.f; Ey[i] = 0.f; Ox[i] = 0.f; Oy[i] = 0.f; }
    const float* src = lig_comb + (b * 2 + f) * NPIX;

    for (int s5 = 0; s5 < 5; ++s5) {
      __syncthreads();   // prev strip's Arow10 consumers + imgS readers done
      // ---- rotate strip rows [10*s5, 10*s5+10) ----
      for (int o = tid; o < 520; o += 256) {
        int i = 10 * s5 + o / 52, j = o % 52;
        float acc = 0.f;
        if (j < 50) {
          float gx = fmaf((float)j, 2.0f / 49.0f, -1.0f);
          float gy = fmaf((float)i, 2.0f / 49.0f, -1.0f);
          float ix = (ca * gx + sa * gy + 1.0f) * 24.5f;
          float iy = (ca * gy - sa * gx + 1.0f) * 24.5f;
          float x0 = floorf(ix), y0 = floorf(iy);
#pragma unroll
          for (int dy = 0; dy < 2; ++dy)
#pragma unroll
            for (int dx = 0; dx < 2; ++dx) {
              float xc = x0 + dx, yc = y0 + dy;
              float w = (1.0f - fabsf(ix - xc)) * (1.0f - fabsf(iy - yc));
              bool valid = (xc >= 0.f) && (xc < 50.f) && (yc >= 0.f) && (yc < 50.f);
              int xi = (int)fminf(fmaxf(xc, 0.f), 49.f);
              int yi = (int)fminf(fmaxf(yc, 0.f), 49.f);
              acc += valid ? w * src[yi * L + xi] : 0.f;
            }
        }
        imgS[o] = acc;
      }
      __syncthreads();
      // ---- rowDFT of strip: 2 rows/thread ----
      if (tid < 255) {
        float are0 = 0.f, aim0 = 0.f, are1 = 0.f, aim1 = 0.f;
        float stx, sty;
        sincosf(PHI * (float)kR, &sty, &stx); sty = -sty;
        const float* i0 = imgS + rl * 52;
        const float* i1 = imgS + (rl + 5) * 52;
        for (int half = 0; half < 2; ++half) {
          float wx, wy;
          int t0 = half ? (24 * kR) % 100 : 0;
          sincosf(PHI * (float)t0, &wy, &wx); wy = -wy;
          int u0 = half ? 6 : 0, u1 = half ? 13 : 6;
          for (int u = u0; u < u1; ++u) {
            float4 q0 = *(const float4*)(i0 + 4 * u);
            float4 q1 = *(const float4*)(i1 + 4 * u);
#pragma unroll
            for (int v = 0; v < 4; ++v) {
              float v0 = (v == 0) ? q0.x : (v == 1) ? q0.y : (v == 2) ? q0.z : q0.w;
              float v1 = (v == 0) ? q1.x : (v == 1) ? q1.y : (v == 2) ? q1.z : q1.w;
              are0 = fmaf(v0, wx, are0); aim0 = fmaf(v0, wy, aim0);
              are1 = fmaf(v1, wx, are1); aim1 = fmaf(v1, wy, aim1);
              CROT(wx, wy, stx, sty);
            }
          }
        }
        Arow10[rl * 52 + kR]       = make_float2(are0, aim0);
        Arow10[(rl + 5) * 52 + kR] = make_float2(are1, aim1);
      }
      __syncthreads();
      // ---- accumulate colDFT E/O partials over this strip's 10 rows ----
      if (act) {
#pragma unroll
        for (int lr = 0; lr < 10; lr += 2) {      // even global r
          const float2* ap = Arow10 + lr * 52 + k0;
#pragma unroll
          for (int i = 0; i < 11; ++i) if (i < W) {
            float2 q = ap[i];
            Ex[i] = fmaf(q.x, ewx, fmaf(-q.y, ewy, Ex[i]));
            Ey[i] = fmaf(q.x, ewy, fmaf( q.y, ewx, Ey[i]));
          }
          CROT(ewx, ewy, s2x, s2y);
        }
#pragma unroll
        for (int lr = 1; lr < 10; lr += 2) {      // odd global r
          const float2* ap = Arow10 + lr * 52 + k0;
#pragma unroll
          for (int i = 0; i < 11; ++i) if (i < W) {
            float2 q = ap[i];
            Ox[i] = fmaf(q.x, owx, fmaf(-q.y, owy, Ox[i]));
            Oy[i] = fmaf(q.x, owy, fmaf( q.y, owx, Oy[i]));
          }
          CROT(owx, owy, s2x, s2y);
        }
      }
    } // s5
    // ---- combine radix-2 halves, multiply F*conj(G), accumulate into P ----
    if (act) {
      const float2* Fa = F1 + (size_t)(b * 2 + f) * ISPEC + mp * IST + k0;
      const float2* Fb = Fa + 50 * IST;
      float2* d0 = P + mp * 52 + k0;
      float2* d1 = d0 + 50 * 52;
#pragma unroll
      for (int i = 0; i < 11; ++i) if (i < W) {
        float gx0 = Ex[i] + Ox[i], gy0 = Ey[i] + Oy[i];
        float gx1 = Ex[i] - Ox[i], gy1 = Ey[i] - Oy[i];
        float2 F0 = Fa[i], Fv1 = Fb[i];
        float p0x = fmaf(F0.x, gx0,  F0.y * gy0);
        float p0y = fmaf(F0.y, gx0, -F0.x * gy0);
        float p1x = fmaf(Fv1.x, gx1,  Fv1.y * gy1);
        float p1y = fmaf(Fv1.y, gx1, -Fv1.x * gy1);
        if (f == 0) { d0[i] = make_float2(p0x, p0y); d1[i] = make_float2(p1x, p1y); }
        else {
          float2 o0 = d0[i], o1 = d1[i];
          d0[i] = make_float2(o0.x + p0x, o0.y + p0y);
          d1[i] = make_float2(o1.x + p1x, o1.y + p1y);
        }
      }
    }
  } // f
  __syncthreads();   // P complete (cross-thread reads next)

  // ---- inverse stage 1 (radix-2 over m parity), in-place transpose:
  //      T[k][rp(+50)] = sum_m P[m][k] e^{+i phi m rp} ----
  if (act) {
#pragma unroll
    for (int i = 0; i < 11; ++i) { Ex[i] = 0.f; Ey[i] = 0.f; Ox[i] = 0.f; Oy[i] = 0.f; }
    float p2x, p2y;
    sincosf(PHI * (float)((2 * mp) % 100), &p2y, &p2x);   // +step
    { float wx = 1.f, wy = 0.f;
      for (int s = 0; s < 50; ++s) {
        if (s == 25) { wx = (mp & 1) ? -1.f : 1.f; wy = 0.f; }
        const float2* pp = P + (2 * s) * 52 + k0;
#pragma unroll
        for (int i = 0; i < 11; ++i) if (i < W) {
          float2 q = pp[i];
          Ex[i] = fmaf(q.x, wx, fmaf(-q.y, wy, Ex[i]));
          Ey[i] = fmaf(q.x, wy, fmaf( q.y, wx, Ey[i]));
        }
        CROT(wx, wy, p2x, p2y);
      } }
    { float wx, wy;
      sincosf(PHI * (float)mp, &wy, &wx);
      for (int s = 0; s < 50; ++s) {
        if (s == 25) { int t0 = (51 * mp) % 100; sincosf(PHI * (float)t0, &wy, &wx); }
        const float2* pp = P + (2 * s + 1) * 52 + k0;
#pragma unroll
        for (int i = 0; i < 11; ++i) if (i < W) {
          float2 q = pp[i];
          Ox[i] = fmaf(q.x, wx, fmaf(-q.y, wy, Ox[i]));
          Oy[i] = fmaf(q.x, wy, fmaf( q.y, wx, Oy[i]));
        }
        CROT(wx, wy, p2x, p2y);
      } }
  }
  __syncthreads();   // ALL P reads done; safe to clobber with T
  if (act) {
#pragma unroll
    for (int i = 0; i < 11; ++i) if (i < W) {
      int k = k0 + i;
      P[k * 100 + mp]      = make_float2(Ex[i] + Ox[i], Ey[i] + Oy[i]);
      P[k * 100 + mp + 50] = make_float2(Ex[i] - Ox[i], Ey[i] - Oy[i]);
    }
  }
  __syncthreads();   // T[k][r] ready

  // ---- inverse stage 2 (radix-2 over k parity) + fftshifted argmax ----
  float best = -3.4e38f;
  int bidx = 0x7fffffff;
  if (act) {
    const int cp = mp;
    const int r0 = kc * 20;                 // 5 chunks x 20 rows
    float e[20], o[20];
#pragma unroll
    for (int i = 0; i < 20; ++i) { e[i] = 0.f; o[i] = 0.f; }
    float q2x, q2y;
    sincosf(PHI * (float)((2 * cp) % 100), &q2y, &q2x);   // step e^{+2i phi c}
    { float wx = q2x, wy = q2y;             // k=2
      for (int s = 1; s < 25; ++s) {
        const float2* tp = P + (2 * s) * 100 + r0;
#pragma unroll
        for (int i = 0; i < 20; ++i) {
          float2 q = tp[i];
          e[i] = fmaf(q.x, wx, fmaf(-q.y, wy, e[i]));
        }
        CROT(wx, wy, q2x, q2y);
      } }
    { float wx, wy;
      sincosf(PHI * (float)cp, &wy, &wx);   // k=1
      for (int s = 0; s < 25; ++s) {
        const float2* tp = P + (2 * s + 1) * 100 + r0;
#pragma unroll
        for (int i = 0; i < 20; ++i) {
          float2 q = tp[i];
          o[i] = fmaf(q.x, wx, fmaf(-q.y, wy, o[i]));
        }
        CROT(wx, wy, q2x, q2y);
      } }
    float sgn = (cp & 1) ? -1.f : 1.f;
    const float2* T0  = P + r0;
    const float2* T50 = P + 50 * 100 + r0;
#pragma unroll
    for (int i = 0; i < 20; ++i) {
      int r = r0 + i;
      float base = T0[i].x + sgn * T50[i].x;
      float X0 = fmaf(2.f, e[i] + o[i], base);   // c = cp
      float X1 = fmaf(2.f, e[i] - o[i], base);   // c = cp + 50
      int xs = r + 50; if (xs >= 100) xs -= 100;
      int f0 = xs * 100 + cp + 50, f1 = xs * 100 + cp;
      if (X0 > best || (X0 == best && f0 < bidx)) { best = X0; bidx = f0; }
      if (X1 > best || (X1 == best && f1 < bidx)) { best = X1; bidx = f1; }
    }
  }
  rv[tid] = best; ri[tid] = bidx;
  __syncthreads();
  for (int s = 128; s > 0; s >>= 1) {
    if (tid < s) {
      float ov = rv[tid + s]; int oi = ri[tid + s];
      if (ov > rv[tid] || (ov == rv[tid] && oi < ri[tid])) { rv[tid] = ov; ri[tid] = oi; }
    }
    __syncthreads();
  }
  if (tid == 0) { pval[ab] = rv[0]; pidx[ab] = a * 10000 + ri[0]; }
}

// ---------------- final per-batch reduction over 120 angles ----------------
__global__ void k_final(const float* __restrict__ pval,
                        const int* __restrict__ pidx, float* __restrict__ out) {
  int b = threadIdx.x;
  if (b >= NB) return;
  float best = -3.4e38f; int bidx = 0x7fffffff;
  for (int a = 0; a < NA; ++a) {
    float v = pval[a * NB + b]; int ix = pidx[a * NB + b];
    if (v > best || (v == best && ix < bidx)) { best = v; bidx = ix; }
  }
  int a = bidx / 10000, rr = bidx % 10000, x = rr / NFULL, y = rr % NFULL;
  out[b] = a * ASTEP;
  out[NB + b * 2 + 0] = (float)(x - L);
  out[NB + b * 2 + 1] = (float)(y - L);
}

extern "C" void kernel_launch(void* const* d_in, const int* in_sizes, int n_in,
                              void* d_out, int out_size, void* d_ws, size_t ws_size,
                              hipStream_t stream) {
  const float* receptor = (const float*)d_in[0];
  const float* ligand   = (const float*)d_in[1];
  const float* conv_w   = (const float*)d_in[2];
  const float* conv_b   = (const float*)d_in[3];
  const float* scorer_w = (const float*)d_in[4];
  // scorer_b (d_in[5]) is argmax-invariant: unused.
  float* ws = (float*)d_ws;
  float* rec_feat = ws + OFF_REC;
  float* lig_comb = ws + OFF_LIG;
  float2* F1      = (float2*)(ws + OFF_F1);
  float* pval     = ws + OFF_PVAL;
  int*   pidx     = (int*)(ws + OFF_PIDX);
  float* out      = (float*)d_out;

  k_conv<<<(NB * NPIX + 255) / 256, 256, 0, stream>>>(
      receptor, ligand, conv_w, conv_b, scorer_w, rec_feat, lig_comb);
  k_fwd_rec<<<16, 256, 0, stream>>>(rec_feat, F1);
  k_dock<<<NA * NB, 256, 0, stream>>>(lig_comb, F1, pval, pidx);
  k_final<<<1, 64, 0, stream>>>(pval, pidx, out);
}